// Round 5
// baseline (616.170 us; speedup 1.0000x reference)
//
#include <hip/hip_runtime.h>
#include <hip/hip_bf16.h>

#define NS 16384   // batch
#define H 256      // hidden
#define TH 768     // 3H
#define PRED 24    // decode steps
#define LDA 272    // LDS h-tile row stride (shorts); R3/R4-verified
#define WS_NEEDED (425984)

typedef short bf16x8 __attribute__((ext_vector_type(8)));
typedef float floatx4 __attribute__((ext_vector_type(4)));

__device__ __forceinline__ float b2f(unsigned short u) {
    return __uint_as_float(((unsigned int)u) << 16);
}
__device__ __forceinline__ unsigned short f2b(float f) {   // RTN-even bf16
    unsigned int u = __float_as_uint(f);
    return (unsigned short)((u + 0x7FFFu + ((u >> 16) & 1u)) >> 16);
}
__device__ __forceinline__ float fsig(float v) {
    return __builtin_amdgcn_rcpf(1.0f + __expf(-v));
}
__device__ __forceinline__ float ftanh(float v) {
    return 1.0f - 2.0f * __builtin_amdgcn_rcpf(1.0f + __expf(2.0f * v));
}

// ================= prep 1: rank-1 input-proj collapse + small vectors =================
__global__ void prep_proj(const void* __restrict__ WihP, const void* __restrict__ wprojP,
                          const void* __restrict__ bprojP, const void* __restrict__ bihP,
                          const void* __restrict__ bhhP, const void* __restrict__ woutP,
                          const void* __restrict__ boutP,
                          float* __restrict__ u, float* __restrict__ c,
                          float* __restrict__ bhn, float* __restrict__ wo,
                          float* __restrict__ b0) {
    const int j = blockIdx.x;        // 768
    const int lane = threadIdx.x;    // 64
    unsigned long long bm = __ballot(!(fabsf(b2f(((const unsigned short*)WihP)[lane])) <= 0.25f));
    const bool f32in = (bm != 0ull);

    float su = 0.f, sc = 0.f;
    if (f32in) {
        const float* row = (const float*)WihP + (size_t)j * H;
        const float* wp = (const float*)wprojP;
        const float* bp = (const float*)bprojP;
        for (int k = lane; k < H; k += 64) {
            float w = row[k];
            su = fmaf(w, wp[k], su); sc = fmaf(w, bp[k], sc);
        }
    } else {
        const unsigned short* row = (const unsigned short*)WihP + (size_t)j * H;
        const unsigned short* wp = (const unsigned short*)wprojP;
        const unsigned short* bp = (const unsigned short*)bprojP;
        for (int k = lane; k < H; k += 64) {
            float w = b2f(row[k]);
            su = fmaf(w, b2f(wp[k]), su); sc = fmaf(w, b2f(bp[k]), sc);
        }
    }
    for (int m = 32; m; m >>= 1) { su += __shfl_xor(su, m, 64); sc += __shfl_xor(sc, m, 64); }

    if (lane == 0) {
        float bih = f32in ? ((const float*)bihP)[j] : b2f(((const unsigned short*)bihP)[j]);
        float bhh = f32in ? ((const float*)bhhP)[j] : b2f(((const unsigned short*)bhhP)[j]);
        u[j] = su;
        c[j] = sc + bih + (j < 512 ? bhh : 0.f);
        if (j >= 512) bhn[j - 512] = bhh;
    }
    if (j < H && lane == 1)
        wo[j] = f32in ? ((const float*)woutP)[j] : b2f(((const unsigned short*)woutP)[j]);
    if (j == 0 && lane == 2)
        b0[0] = f32in ? ((const float*)boutP)[0] : b2f(((const unsigned short*)boutP)[0]);
}

// ================= prep 2: swizzle W_hh into MFMA-fragment-contiguous bf16 =================
// frag fi = (w*8 + kk)*3 + g ; within frag: lane*8 elems (R4-verified).
__global__ void prep_swz(const void* __restrict__ WhhP, unsigned short* __restrict__ Wp) {
    const int cidx = blockIdx.x * 256 + threadIdx.x;
    unsigned long long bm = __ballot(!(fabsf(b2f(((const unsigned short*)WhhP)[threadIdx.x & 63])) <= 0.25f));
    const bool f32in = (bm != 0ull);

    const int lane = cidx & 63;
    const int fi   = cidx >> 6;
    const int g    = fi % 3;
    const int kk   = (fi / 3) & 7;
    const int w    = fi / 24;
    const size_t src = (size_t)(g * 256 + w * 16 + (lane & 15)) * H + kk * 32 + (lane >> 4) * 8;
    unsigned short* dst = Wp + (size_t)cidx * 8;
    if (f32in) {
        const float* s = (const float*)WhhP + src;
#pragma unroll
        for (int e = 0; e < 8; ++e) dst[e] = f2b(s[e]);
    } else {
        const unsigned short* s = (const unsigned short*)WhhP + src;
#pragma unroll
        for (int e = 0; e < 8; ++e) dst[e] = s[e];
    }
}

// ================= fused 24-step decode: resident-W + pipelined streaming =================
// 256 blocks x 1024 thr (16 waves, 4/SIMD => VGPR <= 128 enforced).
// Wave w owns h-cols [16w,16w+16); r,z x kk0-3 frags resident in regs; the other
// 16 frags stream in 4-frag bursts overlapped with MFMA. Output buffered in LDS.
__global__ __launch_bounds__(1024)
void decode_swz(const void* __restrict__ encP, const void* __restrict__ WihP,
                const unsigned short* __restrict__ Wp,
                const float* __restrict__ u, const float* __restrict__ c,
                const float* __restrict__ bhnA, const float* __restrict__ woA,
                const float* __restrict__ b0A, void* __restrict__ outP) {
    __shared__ __align__(16) unsigned short As[64 * LDA];   // 34.8 KB bf16 h tile
    __shared__ float pred_part[16][64];                     // 4 KB
    __shared__ float pred_fin[64];
    __shared__ float pred_out[64][PRED];                    // 6 KB output buffer
    __shared__ int sflag;

    const int tid  = threadIdx.x;
    const int w    = tid >> 6;
    const int lane = tid & 63;
    const int lo   = lane & 15;
    const int quad = lane >> 4;
    const int m0   = blockIdx.x * 64;

    if (tid == 0) sflag = 0;
    __syncthreads();
    if (!(fabsf(b2f(((const unsigned short*)WihP)[tid])) <= 0.25f)) sflag = 1;
    __syncthreads();
    const bool f32in = (sflag != 0);

    const float*          encF = (const float*)encP;
    const unsigned short* encB = (const unsigned short*)encP;

    // stage h0 tile (bf16)
    for (int i = tid; i < 64 * H; i += 1024) {
        int r = i >> 8, col = i & 255;
        float hv = f32in ? encF[(size_t)(m0 + r) * H + col] : b2f(encB[(size_t)(m0 + r) * H + col]);
        As[r * LDA + col] = f2b(hv);
    }
    if (tid < 64) pred_fin[tid] = 0.f;   // start token x=0

    const int jj = w * 16 + lo;
    const float ur = u[jj], uz = u[256 + jj], un = u[512 + jj];
    const float cr = c[jj], cz = c[256 + jj], cn = c[512 + jj];
    const float bh = bhnA[jj], wov = woA[jj];
    const float b0 = b0A[0];

    float hold[4][4];
#pragma unroll
    for (int im = 0; im < 4; ++im)
#pragma unroll
        for (int v = 0; v < 4; ++v) {
            int row = m0 + im * 16 + quad * 4 + v;
            hold[im][v] = f32in ? encF[(size_t)row * H + jj] : b2f(encB[(size_t)row * H + jj]);
        }

    const unsigned short* wpBase = Wp + (size_t)w * 12288 + lane * 8;
    // frag fetch helper index: frag(kk,g) at wpBase + (kk*3+g)*512
#define WFRAG(kk, g) (*(const bf16x8*)(wpBase + ((kk) * 3 + (g)) * 512))

    // ---- resident frags: r,z gates x kk0..3 (8 frags, 32 VGPRs) ----
    bf16x8 wr01[8];
#pragma unroll
    for (int kk = 0; kk < 4; ++kk) {
        wr01[kk * 2 + 0] = WFRAG(kk, 0);
        wr01[kk * 2 + 1] = WFRAG(kk, 1);
    }
    __syncthreads();

#define AFRAG(kk) (*(const bf16x8*)&As[((void)0, 0) + (aRow) * LDA + (kk) * 32 + quad * 8])
    const int aRow0 = lo * LDA + quad * 8;   // base for im=0; row block im adds im*16*LDA

#pragma unroll 1
    for (int t = 0; t < PRED; ++t) {
        floatx4 acc[3][4];
#pragma unroll
        for (int g = 0; g < 3; ++g)
#pragma unroll
            for (int im = 0; im < 4; ++im) acc[g][im] = (floatx4){0.f, 0.f, 0.f, 0.f};

        // ---- S1: issue burst B (n-gate kk0-3), compute resident r,z kk0-3 ----
        bf16x8 bB0 = WFRAG(0, 2), bB1 = WFRAG(1, 2), bB2 = WFRAG(2, 2), bB3 = WFRAG(3, 2);
        bf16x8 aR[4][4];   // A-frags kk0..3 for 4 row-tiles (64 regs transient? no: 4kk x 4im x 4 = 64.. keep per-kk)
#pragma unroll
        for (int kk = 0; kk < 4; ++kk) {
#pragma unroll
            for (int im = 0; im < 4; ++im)
                aR[kk][im] = *(const bf16x8*)&As[(im * 16 + lo) * LDA + kk * 32 + quad * 8];
#pragma unroll
            for (int im = 0; im < 4; ++im) {
                acc[0][im] = __builtin_amdgcn_mfma_f32_16x16x32_bf16(aR[kk][im], wr01[kk * 2 + 0], acc[0][im], 0, 0, 0);
                acc[1][im] = __builtin_amdgcn_mfma_f32_16x16x32_bf16(aR[kk][im], wr01[kk * 2 + 1], acc[1][im], 0, 0, 0);
            }
        }

        // ---- S2: issue burst C (r,z kk4,5), compute n-gate kk0-3 ----
        bf16x8 cB0 = WFRAG(4, 0), cB1 = WFRAG(4, 1), cB2 = WFRAG(5, 0), cB3 = WFRAG(5, 1);
#pragma unroll
        for (int kk = 0; kk < 4; ++kk) {
            bf16x8 bb = (kk == 0) ? bB0 : (kk == 1) ? bB1 : (kk == 2) ? bB2 : bB3;
#pragma unroll
            for (int im = 0; im < 4; ++im)
                acc[2][im] = __builtin_amdgcn_mfma_f32_16x16x32_bf16(aR[kk][im], bb, acc[2][im], 0, 0, 0);
        }

        // ---- S3: issue burst D (r,z kk6,7), compute burst C ----
        bf16x8 dB0 = WFRAG(6, 0), dB1 = WFRAG(6, 1), dB2 = WFRAG(7, 0), dB3 = WFRAG(7, 1);
        bf16x8 a4[4], a5[4];
#pragma unroll
        for (int im = 0; im < 4; ++im) {
            a4[im] = *(const bf16x8*)&As[(im * 16 + lo) * LDA + 4 * 32 + quad * 8];
            a5[im] = *(const bf16x8*)&As[(im * 16 + lo) * LDA + 5 * 32 + quad * 8];
        }
#pragma unroll
        for (int im = 0; im < 4; ++im) {
            acc[0][im] = __builtin_amdgcn_mfma_f32_16x16x32_bf16(a4[im], cB0, acc[0][im], 0, 0, 0);
            acc[1][im] = __builtin_amdgcn_mfma_f32_16x16x32_bf16(a4[im], cB1, acc[1][im], 0, 0, 0);
            acc[0][im] = __builtin_amdgcn_mfma_f32_16x16x32_bf16(a5[im], cB2, acc[0][im], 0, 0, 0);
            acc[1][im] = __builtin_amdgcn_mfma_f32_16x16x32_bf16(a5[im], cB3, acc[1][im], 0, 0, 0);
        }

        // ---- S4: issue burst E (n-gate kk4-7), compute burst D ----
        bf16x8 eB0 = WFRAG(4, 2), eB1 = WFRAG(5, 2), eB2 = WFRAG(6, 2), eB3 = WFRAG(7, 2);
        bf16x8 a6[4], a7[4];
#pragma unroll
        for (int im = 0; im < 4; ++im) {
            a6[im] = *(const bf16x8*)&As[(im * 16 + lo) * LDA + 6 * 32 + quad * 8];
            a7[im] = *(const bf16x8*)&As[(im * 16 + lo) * LDA + 7 * 32 + quad * 8];
        }
#pragma unroll
        for (int im = 0; im < 4; ++im) {
            acc[0][im] = __builtin_amdgcn_mfma_f32_16x16x32_bf16(a6[im], dB0, acc[0][im], 0, 0, 0);
            acc[1][im] = __builtin_amdgcn_mfma_f32_16x16x32_bf16(a6[im], dB1, acc[1][im], 0, 0, 0);
            acc[0][im] = __builtin_amdgcn_mfma_f32_16x16x32_bf16(a7[im], dB2, acc[0][im], 0, 0, 0);
            acc[1][im] = __builtin_amdgcn_mfma_f32_16x16x32_bf16(a7[im], dB3, acc[1][im], 0, 0, 0);
        }

        // ---- S5: compute burst E ----
#pragma unroll
        for (int im = 0; im < 4; ++im) {
            acc[2][im] = __builtin_amdgcn_mfma_f32_16x16x32_bf16(a4[im], eB0, acc[2][im], 0, 0, 0);
            acc[2][im] = __builtin_amdgcn_mfma_f32_16x16x32_bf16(a5[im], eB1, acc[2][im], 0, 0, 0);
            acc[2][im] = __builtin_amdgcn_mfma_f32_16x16x32_bf16(a6[im], eB2, acc[2][im], 0, 0, 0);
            acc[2][im] = __builtin_amdgcn_mfma_f32_16x16x32_bf16(a7[im], eB3, acc[2][im], 0, 0, 0);
        }
        __syncthreads();   // all waves done reading As(t)

        // ---- epilogue: gates + h update + pred partials (R4-verified math) ----
#pragma unroll
        for (int im = 0; im < 4; ++im) {
#pragma unroll
            for (int v = 0; v < 4; ++v) {
                const int row = im * 16 + quad * 4 + v;
                const float xv = pred_fin[row];
                float r  = fsig(fmaf(xv, ur, cr) + acc[0][im][v]);
                float z  = fsig(fmaf(xv, uz, cz) + acc[1][im][v]);
                float n  = ftanh(fmaf(xv, un, cn) + r * (acc[2][im][v] + bh));
                float hn = fmaf(z, hold[im][v] - n, n);
                hold[im][v] = hn;
                As[row * LDA + jj] = f2b(hn);
                float pv = hn * wov;
                pv += __shfl_xor(pv, 1, 64);
                pv += __shfl_xor(pv, 2, 64);
                pv += __shfl_xor(pv, 4, 64);
                pv += __shfl_xor(pv, 8, 64);
                if (lo == 0) pred_part[w][row] = pv;
            }
        }
        __syncthreads();

        if (tid < 64) {
            float pr = b0;
#pragma unroll
            for (int ww = 0; ww < 16; ++ww) pr += pred_part[ww][tid];
            pred_fin[tid] = pr;
            pred_out[tid][t] = pr;       // buffered; written coalesced at end
        }
    }
    __syncthreads();

    // ---- single coalesced output store: rows m0..m0+63, [N,PRED] layout ----
    for (int i = tid; i < 64 * PRED; i += 1024) {
        int row = i / PRED, tt = i % PRED;
        float pr = pred_out[row][tt];
        if (f32in) ((float*)outP)[(size_t)(m0 + row) * PRED + tt] = pr;
        else ((unsigned short*)outP)[(size_t)(m0 + row) * PRED + tt] = f2b(pr);
    }
#undef WFRAG
#undef AFRAG
}

// ================= fallback (R3, proven): zero-workspace fused decode =================
__global__ __launch_bounds__(512, 2)
void decode_all(const void* __restrict__ encP,   const void* __restrict__ wprojP,
                const void* __restrict__ bprojP, const void* __restrict__ WihP,
                const void* __restrict__ bihP,   const void* __restrict__ WhhP,
                const void* __restrict__ bhhP,   const void* __restrict__ woutP,
                const void* __restrict__ boutP,  void* __restrict__ outP) {
    __shared__ __align__(16) unsigned short As[64 * LDA];
    __shared__ float u_lds[TH], c_lds[TH];
    __shared__ float bhn_lds[H], wo_lds[H];
    __shared__ float wp_lds[H], bp_lds[H];
    __shared__ float pred_lds[2][64];
    __shared__ int sflag;

    const int tid  = threadIdx.x;
    const int wid  = tid >> 6;
    const int lane = tid & 63;
    const int lo   = lane & 15;
    const int quad = lane >> 4;
    const int rh   = wid & 3;
    const int ch   = wid >> 2;
    const int m0   = blockIdx.x * 64;

    if (tid == 0) sflag = 0;
    __syncthreads();
    if (!(fabsf(b2f(((const unsigned short*)WihP)[tid])) <= 0.25f)) sflag = 1;
    __syncthreads();
    const bool f32in = (sflag != 0);

    const float*          encF = (const float*)encP;
    const unsigned short* encB = (const unsigned short*)encP;
    const unsigned short* WhhB = (const unsigned short*)WhhP;
    const float*          WhhF = (const float*)WhhP;

    if (tid < H) {
        wp_lds[tid] = f32in ? ((const float*)wprojP)[tid] : b2f(((const unsigned short*)wprojP)[tid]);
        bp_lds[tid] = f32in ? ((const float*)bprojP)[tid] : b2f(((const unsigned short*)bprojP)[tid]);
        wo_lds[tid] = f32in ? ((const float*)woutP)[tid]  : b2f(((const unsigned short*)woutP)[tid]);
    }
    __syncthreads();

    for (int j = tid; j < TH; j += 512) {
        float su = 0.f, sc = 0.f;
        if (f32in) {
            const float* row = (const float*)WihP + (size_t)j * H;
            for (int k = 0; k < H; ++k) { float w = row[k]; su = fmaf(w, wp_lds[k], su); sc = fmaf(w, bp_lds[k], sc); }
        } else {
            const unsigned short* row = (const unsigned short*)WihP + (size_t)j * H;
            for (int k = 0; k < H; ++k) { float w = b2f(row[k]); su = fmaf(w, wp_lds[k], su); sc = fmaf(w, bp_lds[k], sc); }
        }
        float bih = f32in ? ((const float*)bihP)[j] : b2f(((const unsigned short*)bihP)[j]);
        float bhh = f32in ? ((const float*)bhhP)[j] : b2f(((const unsigned short*)bhhP)[j]);
        u_lds[j] = su;
        c_lds[j] = sc + bih + (j < 512 ? bhh : 0.f);
        if (j >= 512) bhn_lds[j - 512] = bhh;
    }

    for (int i = tid; i < 64 * H; i += 512) {
        int r = i >> 8, col = i & 255;
        float hv = f32in ? encF[(size_t)(m0 + r) * H + col] : b2f(encB[(size_t)(m0 + r) * H + col]);
        As[r * LDA + col] = f2b(hv);
    }
    float hold[8][4];
#pragma unroll
    for (int s = 0; s < 8; ++s)
#pragma unroll
        for (int v = 0; v < 4; ++v) {
            int row = m0 + rh * 16 + quad * 4 + v;
            int jj  = ch * 128 + s * 16 + lo;
            hold[s][v] = f32in ? encF[(size_t)row * H + jj] : b2f(encB[(size_t)row * H + jj]);
        }
    const float b0 = f32in ? ((const float*)boutP)[0] : b2f(((const unsigned short*)boutP)[0]);

    float xm[4] = {0.f, 0.f, 0.f, 0.f};
    __syncthreads();

    const int aBase = (rh * 16 + lo) * LDA;
    const int wCol0 = ch * 128 + lo;

#pragma unroll 1
    for (int t = 0; t < PRED; ++t) {
        floatx4 acc[3][8];
#pragma unroll
        for (int g = 0; g < 3; ++g)
#pragma unroll
            for (int s = 0; s < 8; ++s) acc[g][s] = (floatx4){0.f, 0.f, 0.f, 0.f};

        if (f32in) {
#pragma unroll 1
            for (int kk = 0; kk < 8; ++kk) {
                bf16x8 a = *(const bf16x8*)&As[aBase + kk * 32 + quad * 8];
#pragma unroll
                for (int g = 0; g < 3; ++g)
#pragma unroll
                    for (int s = 0; s < 8; ++s) {
                        const float* wr = WhhF + (size_t)(g * 256 + wCol0 + s * 16) * H + kk * 32 + quad * 8;
                        float4 w0 = *(const float4*)wr;
                        float4 w1 = *(const float4*)(wr + 4);
                        bf16x8 b;
                        b[0] = (short)f2b(w0.x); b[1] = (short)f2b(w0.y);
                        b[2] = (short)f2b(w0.z); b[3] = (short)f2b(w0.w);
                        b[4] = (short)f2b(w1.x); b[5] = (short)f2b(w1.y);
                        b[6] = (short)f2b(w1.z); b[7] = (short)f2b(w1.w);
                        acc[g][s] = __builtin_amdgcn_mfma_f32_16x16x32_bf16(a, b, acc[g][s], 0, 0, 0);
                    }
            }
        } else {
#pragma unroll 1
            for (int kk = 0; kk < 8; ++kk) {
                bf16x8 a = *(const bf16x8*)&As[aBase + kk * 32 + quad * 8];
#pragma unroll
                for (int g = 0; g < 3; ++g)
#pragma unroll
                    for (int s = 0; s < 8; ++s) {
                        bf16x8 b = *(const bf16x8*)(WhhB + (size_t)(g * 256 + wCol0 + s * 16) * H + kk * 32 + quad * 8);
                        acc[g][s] = __builtin_amdgcn_mfma_f32_16x16x32_bf16(a, b, acc[g][s], 0, 0, 0);
                    }
            }
        }
        __syncthreads();

        float p[4] = {0.f, 0.f, 0.f, 0.f};
#pragma unroll
        for (int s = 0; s < 8; ++s) {
            const int jj = ch * 128 + s * 16 + lo;
            const float urr = u_lds[jj], uzz = u_lds[256 + jj], unn = u_lds[512 + jj];
            const float crr = c_lds[jj], czz = c_lds[256 + jj], cnn = c_lds[512 + jj];
            const float bhn = bhn_lds[jj], wov = wo_lds[jj];
#pragma unroll
            for (int v = 0; v < 4; ++v) {
                const float xv = xm[v];
                float r  = fsig(fmaf(xv, urr, crr) + acc[0][s][v]);
                float z  = fsig(fmaf(xv, uzz, czz) + acc[1][s][v]);
                float n  = ftanh(fmaf(xv, unn, cnn) + r * (acc[2][s][v] + bhn));
                float hn = fmaf(z, hold[s][v] - n, n);
                hold[s][v] = hn;
                As[(rh * 16 + quad * 4 + v) * LDA + jj] = f2b(hn);
                p[v] = fmaf(hn, wov, p[v]);
            }
        }
#pragma unroll
        for (int v = 0; v < 4; ++v) {
            float pv = p[v];
            pv += __shfl_xor(pv, 1, 64);
            pv += __shfl_xor(pv, 2, 64);
            pv += __shfl_xor(pv, 4, 64);
            pv += __shfl_xor(pv, 8, 64);
            if (lo == 0) pred_lds[ch][rh * 16 + quad * 4 + v] = pv;
        }
        __syncthreads();

#pragma unroll
        for (int v = 0; v < 4; ++v) {
            const int ml = rh * 16 + quad * 4 + v;
            xm[v] = b0 + pred_lds[0][ml] + pred_lds[1][ml];
        }
        if (tid < 64) {
            float pr = b0 + pred_lds[0][tid] + pred_lds[1][tid];
            if (f32in) ((float*)outP)[(size_t)(m0 + tid) * PRED + t] = pr;
            else ((unsigned short*)outP)[(size_t)(m0 + tid) * PRED + t] = f2b(pr);
        }
    }
}

extern "C" void kernel_launch(void* const* d_in, const int* in_sizes, int n_in,
                              void* d_out, int out_size, void* d_ws, size_t ws_size,
                              hipStream_t stream) {
    if (ws_size >= (size_t)WS_NEEDED) {
        char* ws = (char*)d_ws;
        unsigned short* Wp = (unsigned short*)ws;          // 393216 B
        float* u   = (float*)(ws + 393216);
        float* c   = (float*)(ws + 396288);
        float* bhn = (float*)(ws + 399360);
        float* wo  = (float*)(ws + 400384);
        float* b0  = (float*)(ws + 401408);
        prep_proj<<<TH, 64, 0, stream>>>(d_in[3], d_in[1], d_in[2], d_in[4], d_in[6],
                                         d_in[7], d_in[8], u, c, bhn, wo, b0);
        prep_swz<<<96, 256, 0, stream>>>(d_in[5], Wp);
        decode_swz<<<NS / 64, 1024, 0, stream>>>(d_in[0], d_in[3], Wp, u, c, bhn, wo, b0, d_out);
    } else {
        decode_all<<<NS / 64, 512, 0, stream>>>(d_in[0], d_in[1], d_in[2], d_in[3],
                                                d_in[4], d_in[5], d_in[6], d_in[7],
                                                d_in[8], d_out);
    }
}

// Round 6
// 432.243 us; speedup vs baseline: 1.4255x; 1.4255x over previous
//
#include <hip/hip_runtime.h>
#include <hip/hip_bf16.h>

#define NS 16384   // batch
#define H 256      // hidden
#define TH 768     // 3H
#define PRED 24    // decode steps
#define LDA 272    // LDS h-tile row stride (shorts); R3/R4-verified
#define WS_NEEDED (425984)

typedef short bf16x8 __attribute__((ext_vector_type(8)));
typedef float floatx4 __attribute__((ext_vector_type(4)));

__device__ __forceinline__ float b2f(unsigned short u) {
    return __uint_as_float(((unsigned int)u) << 16);
}
__device__ __forceinline__ unsigned short f2b(float f) {   // RTN-even bf16
    unsigned int u = __float_as_uint(f);
    return (unsigned short)((u + 0x7FFFu + ((u >> 16) & 1u)) >> 16);
}
__device__ __forceinline__ float fsig(float v) {
    return __builtin_amdgcn_rcpf(1.0f + __expf(-v));
}
__device__ __forceinline__ float ftanh(float v) {
    return 1.0f - 2.0f * __builtin_amdgcn_rcpf(1.0f + __expf(2.0f * v));
}
// async global->LDS DMA, 16 B per lane; LDS dest = wave-uniform base + lane*16
__device__ __forceinline__ void lds_dma16(const unsigned short* g, unsigned short* l) {
    __builtin_amdgcn_global_load_lds(
        (const __attribute__((address_space(1))) unsigned int*)g,
        (__attribute__((address_space(3))) unsigned int*)l, 16, 0, 0);
}
// s_waitcnt vmcnt(3): vm[3:0]=3, exp=7, lgkm=0xF, vm[5:4]=0  -> 0xF73
#define WAIT_VMCNT3() __builtin_amdgcn_s_waitcnt(0x0F73)

// ================= prep 1: rank-1 input-proj collapse + small vectors =================
__global__ void prep_proj(const void* __restrict__ WihP, const void* __restrict__ wprojP,
                          const void* __restrict__ bprojP, const void* __restrict__ bihP,
                          const void* __restrict__ bhhP, const void* __restrict__ woutP,
                          const void* __restrict__ boutP,
                          float* __restrict__ u, float* __restrict__ c,
                          float* __restrict__ bhn, float* __restrict__ wo,
                          float* __restrict__ b0) {
    const int j = blockIdx.x;        // 768
    const int lane = threadIdx.x;    // 64
    unsigned long long bm = __ballot(!(fabsf(b2f(((const unsigned short*)WihP)[lane])) <= 0.25f));
    const bool f32in = (bm != 0ull);

    float su = 0.f, sc = 0.f;
    if (f32in) {
        const float* row = (const float*)WihP + (size_t)j * H;
        const float* wp = (const float*)wprojP;
        const float* bp = (const float*)bprojP;
        for (int k = lane; k < H; k += 64) {
            float w = row[k];
            su = fmaf(w, wp[k], su); sc = fmaf(w, bp[k], sc);
        }
    } else {
        const unsigned short* row = (const unsigned short*)WihP + (size_t)j * H;
        const unsigned short* wp = (const unsigned short*)wprojP;
        const unsigned short* bp = (const unsigned short*)bprojP;
        for (int k = lane; k < H; k += 64) {
            float w = b2f(row[k]);
            su = fmaf(w, b2f(wp[k]), su); sc = fmaf(w, b2f(bp[k]), sc);
        }
    }
    for (int m = 32; m; m >>= 1) { su += __shfl_xor(su, m, 64); sc += __shfl_xor(sc, m, 64); }

    if (lane == 0) {
        float bih = f32in ? ((const float*)bihP)[j] : b2f(((const unsigned short*)bihP)[j]);
        float bhh = f32in ? ((const float*)bhhP)[j] : b2f(((const unsigned short*)bhhP)[j]);
        u[j] = su;
        c[j] = sc + bih + (j < 512 ? bhh : 0.f);
        if (j >= 512) bhn[j - 512] = bhh;
    }
    if (j < H && lane == 1)
        wo[j] = f32in ? ((const float*)woutP)[j] : b2f(((const unsigned short*)woutP)[j]);
    if (j == 0 && lane == 2)
        b0[0] = f32in ? ((const float*)boutP)[0] : b2f(((const unsigned short*)boutP)[0]);
}

// ================= prep 2: swizzle W_hh into MFMA-fragment-contiguous bf16 =================
// frag fi = (w*8 + kk)*3 + g ; within frag: lane*8 elems (R4-verified).
__global__ void prep_swz(const void* __restrict__ WhhP, unsigned short* __restrict__ Wp) {
    const int cidx = blockIdx.x * 256 + threadIdx.x;
    unsigned long long bm = __ballot(!(fabsf(b2f(((const unsigned short*)WhhP)[threadIdx.x & 63])) <= 0.25f));
    const bool f32in = (bm != 0ull);

    const int lane = cidx & 63;
    const int fi   = cidx >> 6;
    const int g    = fi % 3;
    const int kk   = (fi / 3) & 7;
    const int w    = fi / 24;
    const size_t src = (size_t)(g * 256 + w * 16 + (lane & 15)) * H + kk * 32 + (lane >> 4) * 8;
    unsigned short* dst = Wp + (size_t)cidx * 8;
    if (f32in) {
        const float* s = (const float*)WhhP + src;
#pragma unroll
        for (int e = 0; e < 8; ++e) dst[e] = f2b(s[e]);
    } else {
        const unsigned short* s = (const unsigned short*)WhhP + src;
#pragma unroll
        for (int e = 0; e < 8; ++e) dst[e] = s[e];
    }
}

// ================= fused 24-step decode: LDS-DMA double-buffered W stream =================
// 256 blocks x 1024 thr (16 waves). Wave w owns h-cols [16w,16w+16); acc = 48 AGPR.
// B frags DMA'd global->LDS (no VGPR in-flight), double-buffered per kk in per-wave
// regions; explicit vmcnt(3) gates reads. W is t-invariant so the pipeline runs
// continuously across steps. Output buffered in LDS, stored once.
__global__ __launch_bounds__(1024)
void decode_swz(const void* __restrict__ encP, const void* __restrict__ WihP,
                const unsigned short* __restrict__ Wp,
                const float* __restrict__ u, const float* __restrict__ c,
                const float* __restrict__ bhnA, const float* __restrict__ woA,
                const float* __restrict__ b0A, void* __restrict__ outP) {
    __shared__ __align__(16) unsigned short As[64 * LDA];       // 34.8 KB bf16 h tile
    __shared__ __align__(16) unsigned short Bb[2 * 16 * 3 * 512]; // 96 KB B double-buffer
    __shared__ float pred_part[16][64];                         // 4 KB
    __shared__ float pred_fin[64];
    __shared__ float pred_out[64][PRED];                        // 6 KB
    __shared__ int sflag;

    const int tid  = threadIdx.x;
    const int w    = tid >> 6;
    const int lane = tid & 63;
    const int lo   = lane & 15;
    const int quad = lane >> 4;
    const int m0   = blockIdx.x * 64;

    if (tid == 0) sflag = 0;
    __syncthreads();
    if (!(fabsf(b2f(((const unsigned short*)WihP)[tid])) <= 0.25f)) sflag = 1;
    __syncthreads();
    const bool f32in = (sflag != 0);

    const float*          encF = (const float*)encP;
    const unsigned short* encB = (const unsigned short*)encP;

    // stage h0 tile (bf16)
    for (int i = tid; i < 64 * H; i += 1024) {
        int r = i >> 8, col = i & 255;
        float hv = f32in ? encF[(size_t)(m0 + r) * H + col] : b2f(encB[(size_t)(m0 + r) * H + col]);
        As[r * LDA + col] = f2b(hv);
    }
    if (tid < 64) pred_fin[tid] = 0.f;   // start token x=0

    const int jj = w * 16 + lo;
    const float ur = u[jj], uz = u[256 + jj], un = u[512 + jj];
    const float cr = c[jj], cz = c[256 + jj], cn = c[512 + jj];
    const float bh = bhnA[jj], wov = woA[jj];
    const float b0 = b0A[0];

    float hold[4][4];
#pragma unroll
    for (int im = 0; im < 4; ++im)
#pragma unroll
        for (int v = 0; v < 4; ++v) {
            int row = m0 + im * 16 + quad * 4 + v;
            hold[im][v] = f32in ? encF[(size_t)row * H + jj] : b2f(encB[(size_t)row * H + jj]);
        }

    // wave-local W source / LDS-dest bases
    const unsigned short* wpBase = Wp + (size_t)w * 12288 + lane * 8;  // +(kk*3+g)*512
    unsigned short* bbBase0 = &Bb[(size_t)(0 * 16 + w) * 3 * 512];     // buf0, this wave
    unsigned short* bbBase1 = &Bb[(size_t)(1 * 16 + w) * 3 * 512];     // buf1, this wave

    // preload kk=0 into buf0 (3 frags)
#pragma unroll
    for (int g = 0; g < 3; ++g)
        lds_dma16(wpBase + g * 512, bbBase0 + g * 512);

    __syncthreads();   // As(h0) visible (also drains the preload DMA - fine)

#pragma unroll 1
    for (int t = 0; t < PRED; ++t) {
        floatx4 acc[3][4];
#pragma unroll
        for (int g = 0; g < 3; ++g)
#pragma unroll
            for (int im = 0; im < 4; ++im) acc[g][im] = (floatx4){0.f, 0.f, 0.f, 0.f};

#pragma unroll
        for (int kk = 0; kk < 8; ++kk) {
            // prefetch next chunk (kk+1, or kk=0 for the NEXT step: W is t-invariant)
            const int nk = (kk + 1) & 7;
            unsigned short* nbuf = ((kk + 1) & 1) ? bbBase1 : bbBase0;
#pragma unroll
            for (int g = 0; g < 3; ++g)
                lds_dma16(wpBase + (nk * 3 + g) * 512, nbuf + g * 512);

            // wait until only the 3 just-issued remain outstanding -> chunk kk ready
            WAIT_VMCNT3();

            const unsigned short* cbuf = (kk & 1) ? bbBase1 : bbBase0;
            bf16x8 b[3];
#pragma unroll
            for (int g = 0; g < 3; ++g)
                b[g] = *(const bf16x8*)(cbuf + g * 512 + lane * 8);
            bf16x8 a[4];
#pragma unroll
            for (int im = 0; im < 4; ++im)
                a[im] = *(const bf16x8*)&As[(im * 16 + lo) * LDA + kk * 32 + quad * 8];
#pragma unroll
            for (int g = 0; g < 3; ++g)
#pragma unroll
                for (int im = 0; im < 4; ++im)
                    acc[g][im] = __builtin_amdgcn_mfma_f32_16x16x32_bf16(a[im], b[g], acc[g][im], 0, 0, 0);
        }
        __syncthreads();   // all waves done reading As(t)

        // ---- epilogue: gates + h update + pred partials (R4-verified) ----
#pragma unroll
        for (int im = 0; im < 4; ++im) {
#pragma unroll
            for (int v = 0; v < 4; ++v) {
                const int row = im * 16 + quad * 4 + v;
                const float xv = pred_fin[row];
                float r  = fsig(fmaf(xv, ur, cr) + acc[0][im][v]);
                float z  = fsig(fmaf(xv, uz, cz) + acc[1][im][v]);
                float n  = ftanh(fmaf(xv, un, cn) + r * (acc[2][im][v] + bh));
                float hn = fmaf(z, hold[im][v] - n, n);   // (1-z)*n + z*h
                hold[im][v] = hn;
                As[row * LDA + jj] = f2b(hn);
                float pv = hn * wov;
                pv += __shfl_xor(pv, 1, 64);
                pv += __shfl_xor(pv, 2, 64);
                pv += __shfl_xor(pv, 4, 64);
                pv += __shfl_xor(pv, 8, 64);
                if (lo == 0) pred_part[w][row] = pv;
            }
        }
        __syncthreads();   // As(t+1) + partials visible

        if (tid < 64) {
            float pr = b0;
#pragma unroll
            for (int ww = 0; ww < 16; ++ww) pr += pred_part[ww][tid];
            pred_fin[tid] = pr;
            pred_out[tid][t] = pr;       // buffered; stored coalesced at end
        }
    }
    __syncthreads();

    // single coalesced output store
    for (int i = tid; i < 64 * PRED; i += 1024) {
        int row = i / PRED, tt = i % PRED;
        float pr = pred_out[row][tt];
        if (f32in) ((float*)outP)[(size_t)(m0 + row) * PRED + tt] = pr;
        else ((unsigned short*)outP)[(size_t)(m0 + row) * PRED + tt] = f2b(pr);
    }
}

// ================= fallback (R3, proven): zero-workspace fused decode =================
__global__ __launch_bounds__(512, 2)
void decode_all(const void* __restrict__ encP,   const void* __restrict__ wprojP,
                const void* __restrict__ bprojP, const void* __restrict__ WihP,
                const void* __restrict__ bihP,   const void* __restrict__ WhhP,
                const void* __restrict__ bhhP,   const void* __restrict__ woutP,
                const void* __restrict__ boutP,  void* __restrict__ outP) {
    __shared__ __align__(16) unsigned short As[64 * LDA];
    __shared__ float u_lds[TH], c_lds[TH];
    __shared__ float bhn_lds[H], wo_lds[H];
    __shared__ float wp_lds[H], bp_lds[H];
    __shared__ float pred_lds[2][64];
    __shared__ int sflag;

    const int tid  = threadIdx.x;
    const int wid  = tid >> 6;
    const int lane = tid & 63;
    const int lo   = lane & 15;
    const int quad = lane >> 4;
    const int rh   = wid & 3;
    const int ch   = wid >> 2;
    const int m0   = blockIdx.x * 64;

    if (tid == 0) sflag = 0;
    __syncthreads();
    if (!(fabsf(b2f(((const unsigned short*)WihP)[tid])) <= 0.25f)) sflag = 1;
    __syncthreads();
    const bool f32in = (sflag != 0);

    const float*          encF = (const float*)encP;
    const unsigned short* encB = (const unsigned short*)encP;
    const unsigned short* WhhB = (const unsigned short*)WhhP;
    const float*          WhhF = (const float*)WhhP;

    if (tid < H) {
        wp_lds[tid] = f32in ? ((const float*)wprojP)[tid] : b2f(((const unsigned short*)wprojP)[tid]);
        bp_lds[tid] = f32in ? ((const float*)bprojP)[tid] : b2f(((const unsigned short*)bprojP)[tid]);
        wo_lds[tid] = f32in ? ((const float*)woutP)[tid]  : b2f(((const unsigned short*)woutP)[tid]);
    }
    __syncthreads();

    for (int j = tid; j < TH; j += 512) {
        float su = 0.f, sc = 0.f;
        if (f32in) {
            const float* row = (const float*)WihP + (size_t)j * H;
            for (int k = 0; k < H; ++k) { float w = row[k]; su = fmaf(w, wp_lds[k], su); sc = fmaf(w, bp_lds[k], sc); }
        } else {
            const unsigned short* row = (const unsigned short*)WihP + (size_t)j * H;
            for (int k = 0; k < H; ++k) { float w = b2f(row[k]); su = fmaf(w, wp_lds[k], su); sc = fmaf(w, bp_lds[k], sc); }
        }
        float bih = f32in ? ((const float*)bihP)[j] : b2f(((const unsigned short*)bihP)[j]);
        float bhh = f32in ? ((const float*)bhhP)[j] : b2f(((const unsigned short*)bhhP)[j]);
        u_lds[j] = su;
        c_lds[j] = sc + bih + (j < 512 ? bhh : 0.f);
        if (j >= 512) bhn_lds[j - 512] = bhh;
    }

    for (int i = tid; i < 64 * H; i += 512) {
        int r = i >> 8, col = i & 255;
        float hv = f32in ? encF[(size_t)(m0 + r) * H + col] : b2f(encB[(size_t)(m0 + r) * H + col]);
        As[r * LDA + col] = f2b(hv);
    }
    float hold[8][4];
#pragma unroll
    for (int s = 0; s < 8; ++s)
#pragma unroll
        for (int v = 0; v < 4; ++v) {
            int row = m0 + rh * 16 + quad * 4 + v;
            int jj  = ch * 128 + s * 16 + lo;
            hold[s][v] = f32in ? encF[(size_t)row * H + jj] : b2f(encB[(size_t)row * H + jj]);
        }
    const float b0 = f32in ? ((const float*)boutP)[0] : b2f(((const unsigned short*)boutP)[0]);

    float xm[4] = {0.f, 0.f, 0.f, 0.f};
    __syncthreads();

    const int aBase = (rh * 16 + lo) * LDA;
    const int wCol0 = ch * 128 + lo;

#pragma unroll 1
    for (int t = 0; t < PRED; ++t) {
        floatx4 acc[3][8];
#pragma unroll
        for (int g = 0; g < 3; ++g)
#pragma unroll
            for (int s = 0; s < 8; ++s) acc[g][s] = (floatx4){0.f, 0.f, 0.f, 0.f};

        if (f32in) {
#pragma unroll 1
            for (int kk = 0; kk < 8; ++kk) {
                bf16x8 a = *(const bf16x8*)&As[aBase + kk * 32 + quad * 8];
#pragma unroll
                for (int g = 0; g < 3; ++g)
#pragma unroll
                    for (int s = 0; s < 8; ++s) {
                        const float* wr = WhhF + (size_t)(g * 256 + wCol0 + s * 16) * H + kk * 32 + quad * 8;
                        float4 w0 = *(const float4*)wr;
                        float4 w1 = *(const float4*)(wr + 4);
                        bf16x8 b;
                        b[0] = (short)f2b(w0.x); b[1] = (short)f2b(w0.y);
                        b[2] = (short)f2b(w0.z); b[3] = (short)f2b(w0.w);
                        b[4] = (short)f2b(w1.x); b[5] = (short)f2b(w1.y);
                        b[6] = (short)f2b(w1.z); b[7] = (short)f2b(w1.w);
                        acc[g][s] = __builtin_amdgcn_mfma_f32_16x16x32_bf16(a, b, acc[g][s], 0, 0, 0);
                    }
            }
        } else {
#pragma unroll 1
            for (int kk = 0; kk < 8; ++kk) {
                bf16x8 a = *(const bf16x8*)&As[aBase + kk * 32 + quad * 8];
#pragma unroll
                for (int g = 0; g < 3; ++g)
#pragma unroll
                    for (int s = 0; s < 8; ++s) {
                        bf16x8 b = *(const bf16x8*)(WhhB + (size_t)(g * 256 + wCol0 + s * 16) * H + kk * 32 + quad * 8);
                        acc[g][s] = __builtin_amdgcn_mfma_f32_16x16x32_bf16(a, b, acc[g][s], 0, 0, 0);
                    }
            }
        }
        __syncthreads();

        float p[4] = {0.f, 0.f, 0.f, 0.f};
#pragma unroll
        for (int s = 0; s < 8; ++s) {
            const int jj = ch * 128 + s * 16 + lo;
            const float urr = u_lds[jj], uzz = u_lds[256 + jj], unn = u_lds[512 + jj];
            const float crr = c_lds[jj], czz = c_lds[256 + jj], cnn = c_lds[512 + jj];
            const float bhn = bhn_lds[jj], wov = wo_lds[jj];
#pragma unroll
            for (int v = 0; v < 4; ++v) {
                const float xv = xm[v];
                float r  = fsig(fmaf(xv, urr, crr) + acc[0][s][v]);
                float z  = fsig(fmaf(xv, uzz, czz) + acc[1][s][v]);
                float n  = ftanh(fmaf(xv, unn, cnn) + r * (acc[2][s][v] + bhn));
                float hn = fmaf(z, hold[s][v] - n, n);
                hold[s][v] = hn;
                As[(rh * 16 + quad * 4 + v) * LDA + jj] = f2b(hn);
                p[v] = fmaf(hn, wov, p[v]);
            }
        }
#pragma unroll
        for (int v = 0; v < 4; ++v) {
            float pv = p[v];
            pv += __shfl_xor(pv, 1, 64);
            pv += __shfl_xor(pv, 2, 64);
            pv += __shfl_xor(pv, 4, 64);
            pv += __shfl_xor(pv, 8, 64);
            if (lo == 0) pred_lds[ch][rh * 16 + quad * 4 + v] = pv;
        }
        __syncthreads();

#pragma unroll
        for (int v = 0; v < 4; ++v) {
            const int ml = rh * 16 + quad * 4 + v;
            xm[v] = b0 + pred_lds[0][ml] + pred_lds[1][ml];
        }
        if (tid < 64) {
            float pr = b0 + pred_lds[0][tid] + pred_lds[1][tid];
            if (f32in) ((float*)outP)[(size_t)(m0 + tid) * PRED + t] = pr;
            else ((unsigned short*)outP)[(size_t)(m0 + tid) * PRED + t] = f2b(pr);
        }
    }
}

extern "C" void kernel_launch(void* const* d_in, const int* in_sizes, int n_in,
                              void* d_out, int out_size, void* d_ws, size_t ws_size,
                              hipStream_t stream) {
    if (ws_size >= (size_t)WS_NEEDED) {
        char* ws = (char*)d_ws;
        unsigned short* Wp = (unsigned short*)ws;          // 393216 B
        float* u   = (float*)(ws + 393216);
        float* c   = (float*)(ws + 396288);
        float* bhn = (float*)(ws + 399360);
        float* wo  = (float*)(ws + 400384);
        float* b0  = (float*)(ws + 401408);
        prep_proj<<<TH, 64, 0, stream>>>(d_in[3], d_in[1], d_in[2], d_in[4], d_in[6],
                                         d_in[7], d_in[8], u, c, bhn, wo, b0);
        prep_swz<<<96, 256, 0, stream>>>(d_in[5], Wp);
        decode_swz<<<NS / 64, 1024, 0, stream>>>(d_in[0], d_in[3], Wp, u, c, bhn, wo, b0, d_out);
    } else {
        decode_all<<<NS / 64, 512, 0, stream>>>(d_in[0], d_in[1], d_in[2], d_in[3],
                                                d_in[4], d_in[5], d_in[6], d_in[7],
                                                d_in[8], d_out);
    }
}